// Round 1
// baseline (2944.064 us; speedup 1.0000x reference)
//
#include <hip/hip_runtime.h>

#define D 128
#define TN 64

// ---------------------------------------------------------------------------
// Probe: is edge_index stored as int64 (odd 32-bit words all zero) or int32?
// ---------------------------------------------------------------------------
__global__ void detect_kernel(const unsigned int* __restrict__ ei, int* __restrict__ flag) {
    int all0 = 1;
    for (int i = 0; i < 128; ++i) {
        if (ei[2 * i + 1] != 0u) { all0 = 0; break; }
    }
    *flag = all0;   // 1 => int64 layout, 0 => int32 layout
}

// ---------------------------------------------------------------------------
// Scatter-add: agg[dst] += x[src] for each edge. 64 lanes per edge, float2/lane.
// ---------------------------------------------------------------------------
__global__ __launch_bounds__(256) void scatter_kernel(
    const float* __restrict__ x, const void* __restrict__ ei,
    const int* __restrict__ flag, float* __restrict__ agg, int n_edges)
{
    int e = blockIdx.x * 4 + (threadIdx.x >> 6);
    if (e >= n_edges) return;
    int lane = threadIdx.x & 63;
    long long s, d;
    if (*flag) {
        const long long* p = (const long long*)ei;
        s = p[e]; d = p[n_edges + e];
    } else {
        const int* p = (const int*)ei;
        s = p[e]; d = p[n_edges + e];
    }
    float2 v = ((const float2*)(x + s * D))[lane];
    float* a = agg + d * D + (long long)lane * 2;
#if defined(__HIP_DEVICE_COMPILE__)
    unsafeAtomicAdd(a, v.x);
    unsafeAtomicAdd(a + 1, v.y);
#else
    atomicAdd(a, v.x);
    atomicAdd(a + 1, v.y);
#endif
}

// ---------------------------------------------------------------------------
// Fused GEMM + bias + relu:  out = relu(X @ Wr + A @ Wl + b)
// X, A: [n][128] f32; Wr, Wl: [128][128]; out: [n][128]
// Block: 256 threads, tile 64 nodes x 128 cols; each thread 8 rows x 4 cols.
// ---------------------------------------------------------------------------
__global__ __launch_bounds__(256) void gemm_relu_kernel(
    const float* __restrict__ X, const float* __restrict__ A,
    const float* __restrict__ Wr, const float* __restrict__ Wl,
    const float* __restrict__ b, float* __restrict__ out, int n)
{
    __shared__ float sX[TN][D];   // 32 KB
    __shared__ float sA[TN][D];   // 32 KB
    __shared__ float sW[32][D];   // 16 KB
    const int tid = threadIdx.x;
    const int node0 = blockIdx.x * TN;

    // Stage X and A tiles (float4, fully coalesced)
    for (int i = 0; i < 8; ++i) {
        int idx = tid + i * 256;       // 2048 float4 per tile
        int r  = idx >> 5;             // 32 float4 per row
        int c4 = idx & 31;
        long long row = node0 + r;
        float4 vx = make_float4(0.f, 0.f, 0.f, 0.f), va = vx;
        if (row < n) {
            vx = ((const float4*)(X + row * D))[c4];
            va = ((const float4*)(A + row * D))[c4];
        }
        *(float4*)&sX[r][c4 * 4] = vx;
        *(float4*)&sA[r][c4 * 4] = va;
    }

    const int row_g = tid >> 5;   // 0..7  -> rows row_g*8 .. +8
    const int col_g = tid & 31;   // 0..31 -> cols col_g*4 .. +4
    const int c0 = col_g * 4;
    float4 bv = *(const float4*)&b[c0];
    float acc[8][4];
    for (int rr = 0; rr < 8; ++rr) {
        acc[rr][0] = bv.x; acc[rr][1] = bv.y; acc[rr][2] = bv.z; acc[rr][3] = bv.w;
    }

    for (int kc = 0; kc < 8; ++kc) {
        __syncthreads();
        // stage W chunk: 32 rows of (kc<4 ? Wr : Wl), k0 = (kc&3)*32
        const float* Wsrc = (kc < 4) ? Wr : Wl;
        const int k0 = (kc & 3) * 32;
        for (int i = 0; i < 4; ++i) {
            int idx = tid + i * 256;   // 1024 float4 in 32x128
            int r  = idx >> 5;
            int c4 = idx & 31;
            *(float4*)&sW[r][c4 * 4] = ((const float4*)(Wsrc + (long long)(k0 + r) * D))[c4];
        }
        __syncthreads();
        const float (*sIn)[D] = (kc < 4) ? sX : sA;
        #pragma unroll
        for (int kk = 0; kk < 32; ++kk) {
            float4 w = *(const float4*)&sW[kk][c0];
            #pragma unroll
            for (int rr = 0; rr < 8; ++rr) {
                float iv = sIn[row_g * 8 + rr][k0 + kk];
                acc[rr][0] += iv * w.x;
                acc[rr][1] += iv * w.y;
                acc[rr][2] += iv * w.z;
                acc[rr][3] += iv * w.w;
            }
        }
    }

    for (int rr = 0; rr < 8; ++rr) {
        long long row = node0 + row_g * 8 + rr;
        if (row < n) {
            float4 v;
            v.x = fmaxf(acc[rr][0], 0.f);
            v.y = fmaxf(acc[rr][1], 0.f);
            v.z = fmaxf(acc[rr][2], 0.f);
            v.w = fmaxf(acc[rr][3], 0.f);
            *(float4*)&out[row * D + c0] = v;
        }
    }
}

extern "C" void kernel_launch(void* const* d_in, const int* in_sizes, int n_in,
                              void* d_out, int out_size, void* d_ws, size_t ws_size,
                              hipStream_t stream) {
    const float* x   = (const float*)d_in[0];
    const void*  ei  = d_in[1];
    const float* Wr1 = (const float*)d_in[2];
    const float* Wl1 = (const float*)d_in[3];
    const float* b1  = (const float*)d_in[4];
    const float* Wr2 = (const float*)d_in[5];
    const float* Wl2 = (const float*)d_in[6];
    const float* b2  = (const float*)d_in[7];
    float* out = (float*)d_out;

    const int n_nodes = in_sizes[0] / D;
    const int n_edges = in_sizes[1] / 2;

    int*   flag = (int*)d_ws;
    float* agg  = (float*)((char*)d_ws + 256);
    const size_t aggBytes = (size_t)n_nodes * D * sizeof(float);

    const int scatter_blocks = (n_edges + 3) / 4;
    const int gemm_blocks = (n_nodes + TN - 1) / TN;

    detect_kernel<<<1, 1, 0, stream>>>((const unsigned int*)ei, flag);

    // ---- layer 1 ----
    hipMemsetAsync(agg, 0, aggBytes, stream);
    scatter_kernel<<<scatter_blocks, 256, 0, stream>>>(x, ei, flag, agg, n_edges);
    gemm_relu_kernel<<<gemm_blocks, 256, 0, stream>>>(x, agg, Wr1, Wl1, b1, out, n_nodes);

    // ---- layer 2 (h lives in d_out; final GEMM updates d_out in place) ----
    hipMemsetAsync(agg, 0, aggBytes, stream);
    scatter_kernel<<<scatter_blocks, 256, 0, stream>>>(out, ei, flag, agg, n_edges);
    gemm_relu_kernel<<<gemm_blocks, 256, 0, stream>>>(out, agg, Wr2, Wl2, b2, out, n_nodes);
}

// Round 2
// 840.004 us; speedup vs baseline: 3.5048x; 3.5048x over previous
//
#include <hip/hip_runtime.h>

#define D 128

// ---------------------------------------------------------------------------
// Probe: is edge_index stored as int64 (odd 32-bit words all zero) or int32?
// ---------------------------------------------------------------------------
__global__ void detect_kernel(const unsigned int* __restrict__ ei, int* __restrict__ flag) {
    int all0 = 1;
    for (int i = 0; i < 128; ++i) {
        if (ei[2 * i + 1] != 0u) { all0 = 0; break; }
    }
    *flag = all0;   // 1 => int64 layout, 0 => int32 layout
}

__device__ __forceinline__ void load_edge(const void* ei, int flag, int e, int n_edges,
                                          int& s, int& d) {
    if (flag) {
        const long long* p = (const long long*)ei;
        s = (int)p[e]; d = (int)p[n_edges + e];
    } else {
        const int* p = (const int*)ei;
        s = p[e]; d = p[n_edges + e];
    }
}

// ---------------------------------------------------------------------------
// CSR build: histogram -> block scan -> block-sum scan -> add offsets -> fill
// ---------------------------------------------------------------------------
__global__ __launch_bounds__(256) void hist_kernel(
    const void* __restrict__ ei, const int* __restrict__ flag,
    int* __restrict__ deg, int n_edges)
{
    int e = blockIdx.x * 256 + threadIdx.x;
    if (e >= n_edges) return;
    int s, d;
    load_edge(ei, *flag, e, n_edges, s, d);
    atomicAdd(&deg[d], 1);
}

__global__ __launch_bounds__(1024) void scan1_kernel(
    int* __restrict__ arr, int* __restrict__ blockSums, int n)
{
    __shared__ int sm[1024];
    const int tid = threadIdx.x;
    const int i = blockIdx.x * 1024 + tid;
    int v = (i < n) ? arr[i] : 0;
    int val = v;
    sm[tid] = val;
    __syncthreads();
    for (int off = 1; off < 1024; off <<= 1) {
        int t = (tid >= off) ? sm[tid - off] : 0;
        __syncthreads();
        val += t;
        sm[tid] = val;
        __syncthreads();
    }
    if (i < n) arr[i] = val - v;                  // exclusive within block
    if (tid == 1023) blockSums[blockIdx.x] = val; // block total
}

__global__ void scan2_kernel(int* __restrict__ blockSums, int nb,
                             int* __restrict__ row_start, int n)
{
    int run = 0;
    for (int b = 0; b < nb; ++b) {
        int t = blockSums[b];
        blockSums[b] = run;
        run += t;
    }
    row_start[n] = run;   // grand total == n_edges
}

__global__ __launch_bounds__(1024) void scan3_kernel(
    int* __restrict__ row_start, int* __restrict__ cursor,
    const int* __restrict__ blockSums, int n)
{
    const int i = blockIdx.x * 1024 + threadIdx.x;
    if (i >= n) return;
    int rs = row_start[i] + blockSums[blockIdx.x];
    row_start[i] = rs;
    cursor[i] = rs;
}

__global__ __launch_bounds__(256) void fill_kernel(
    const void* __restrict__ ei, const int* __restrict__ flag,
    int* __restrict__ cursor, int* __restrict__ sorted_src, int n_edges)
{
    int e = blockIdx.x * 256 + threadIdx.x;
    if (e >= n_edges) return;
    int s, d;
    load_edge(ei, *flag, e, n_edges, s, d);
    int pos = atomicAdd(&cursor[d], 1);
    sorted_src[pos] = s;
}

// ---------------------------------------------------------------------------
// Aggregation via CSR gather: one wave per node, float2 per lane (128 f32/row).
// Writes every row (zeros for degree-0), so no memset needed.
// ---------------------------------------------------------------------------
__global__ __launch_bounds__(256) void agg_kernel(
    const float* __restrict__ x, const int* __restrict__ sorted_src,
    const int* __restrict__ row_start, float* __restrict__ agg, int n)
{
    const int node = blockIdx.x * 4 + (threadIdx.x >> 6);
    if (node >= n) return;
    const int lane = threadIdx.x & 63;
    const int beg = row_start[node];
    const int end = row_start[node + 1];
    float2 acc = make_float2(0.f, 0.f);
    for (int i = beg; i < end; ++i) {
        int s = sorted_src[i];
        float2 v = ((const float2*)(x + (long long)s * D))[lane];
        acc.x += v.x;
        acc.y += v.y;
    }
    ((float2*)(agg + (long long)node * D))[lane] = acc;
}

// ---------------------------------------------------------------------------
// Fallback scatter (round-1 path) if ws_size is too small for CSR.
// ---------------------------------------------------------------------------
__global__ __launch_bounds__(256) void scatter_kernel(
    const float* __restrict__ x, const void* __restrict__ ei,
    const int* __restrict__ flag, float* __restrict__ agg, int n_edges)
{
    int e = blockIdx.x * 4 + (threadIdx.x >> 6);
    if (e >= n_edges) return;
    int lane = threadIdx.x & 63;
    int s, d;
    load_edge(ei, *flag, e, n_edges, s, d);
    float2 v = ((const float2*)(x + (long long)s * D))[lane];
    float* a = agg + (long long)d * D + lane * 2;
    unsafeAtomicAdd(a, v.x);
    unsafeAtomicAdd(a + 1, v.y);
}

// ---------------------------------------------------------------------------
// Fused GEMM + bias + relu:  out = relu(X @ Wr + A @ Wl + b)
// Block: 256 threads, tile 64 nodes x 128 cols; each thread 8 rows x 4 cols.
// ---------------------------------------------------------------------------
#define TN 64
__global__ __launch_bounds__(256) void gemm_relu_kernel(
    const float* __restrict__ X, const float* __restrict__ A,
    const float* __restrict__ Wr, const float* __restrict__ Wl,
    const float* __restrict__ b, float* __restrict__ out, int n)
{
    __shared__ float sX[TN][D];   // 32 KB
    __shared__ float sA[TN][D];   // 32 KB
    __shared__ float sW[32][D];   // 16 KB
    const int tid = threadIdx.x;
    const int node0 = blockIdx.x * TN;

    for (int i = 0; i < 8; ++i) {
        int idx = tid + i * 256;
        int r  = idx >> 5;
        int c4 = idx & 31;
        long long row = node0 + r;
        float4 vx = make_float4(0.f, 0.f, 0.f, 0.f), va = vx;
        if (row < n) {
            vx = ((const float4*)(X + row * D))[c4];
            va = ((const float4*)(A + row * D))[c4];
        }
        *(float4*)&sX[r][c4 * 4] = vx;
        *(float4*)&sA[r][c4 * 4] = va;
    }

    const int row_g = tid >> 5;
    const int col_g = tid & 31;
    const int c0 = col_g * 4;
    float4 bv = *(const float4*)&b[c0];
    float acc[8][4];
    for (int rr = 0; rr < 8; ++rr) {
        acc[rr][0] = bv.x; acc[rr][1] = bv.y; acc[rr][2] = bv.z; acc[rr][3] = bv.w;
    }

    for (int kc = 0; kc < 8; ++kc) {
        __syncthreads();
        const float* Wsrc = (kc < 4) ? Wr : Wl;
        const int k0 = (kc & 3) * 32;
        for (int i = 0; i < 4; ++i) {
            int idx = tid + i * 256;
            int r  = idx >> 5;
            int c4 = idx & 31;
            *(float4*)&sW[r][c4 * 4] = ((const float4*)(Wsrc + (long long)(k0 + r) * D))[c4];
        }
        __syncthreads();
        const float (*sIn)[D] = (kc < 4) ? sX : sA;
        #pragma unroll
        for (int kk = 0; kk < 32; ++kk) {
            float4 w = *(const float4*)&sW[kk][c0];
            #pragma unroll
            for (int rr = 0; rr < 8; ++rr) {
                float iv = sIn[row_g * 8 + rr][k0 + kk];
                acc[rr][0] += iv * w.x;
                acc[rr][1] += iv * w.y;
                acc[rr][2] += iv * w.z;
                acc[rr][3] += iv * w.w;
            }
        }
    }

    for (int rr = 0; rr < 8; ++rr) {
        long long row = node0 + row_g * 8 + rr;
        if (row < n) {
            float4 v;
            v.x = fmaxf(acc[rr][0], 0.f);
            v.y = fmaxf(acc[rr][1], 0.f);
            v.z = fmaxf(acc[rr][2], 0.f);
            v.w = fmaxf(acc[rr][3], 0.f);
            *(float4*)&out[row * D + c0] = v;
        }
    }
}

static inline size_t align_up(size_t v, size_t a) { return (v + a - 1) & ~(a - 1); }

extern "C" void kernel_launch(void* const* d_in, const int* in_sizes, int n_in,
                              void* d_out, int out_size, void* d_ws, size_t ws_size,
                              hipStream_t stream) {
    const float* x   = (const float*)d_in[0];
    const void*  ei  = d_in[1];
    const float* Wr1 = (const float*)d_in[2];
    const float* Wl1 = (const float*)d_in[3];
    const float* b1  = (const float*)d_in[4];
    const float* Wr2 = (const float*)d_in[5];
    const float* Wl2 = (const float*)d_in[6];
    const float* b2  = (const float*)d_in[7];
    float* out = (float*)d_out;

    const int n_nodes = in_sizes[0] / D;
    const int n_edges = in_sizes[1] / 2;
    const size_t aggBytes = (size_t)n_nodes * D * sizeof(float);

    // ws layout
    char* ws = (char*)d_ws;
    size_t off_flag   = 0;
    size_t off_rs     = 256;                                        // (n+1) ints
    size_t off_cursor = align_up(off_rs + 4 * (size_t)(n_nodes + 1), 256);
    size_t off_bsums  = align_up(off_cursor + 4 * (size_t)n_nodes, 256);   // <=1024 ints
    size_t off_ssrc   = align_up(off_bsums + 4 * 1024, 256);
    size_t off_agg    = align_up(off_ssrc + 4 * (size_t)n_edges, 256);
    size_t required   = off_agg + aggBytes;

    int*   flag       = (int*)(ws + off_flag);
    int*   row_start  = (int*)(ws + off_rs);
    int*   cursor     = (int*)(ws + off_cursor);
    int*   blockSums  = (int*)(ws + off_bsums);
    int*   sorted_src = (int*)(ws + off_ssrc);

    const int edge_blocks = (n_edges + 255) / 256;
    const int gemm_blocks = (n_nodes + TN - 1) / TN;
    const int agg_blocks  = (n_nodes + 3) / 4;
    const int nb          = (n_nodes + 1023) / 1024;

    detect_kernel<<<1, 1, 0, stream>>>((const unsigned int*)ei, flag);

    if (ws_size >= required) {
        float* agg = (float*)(ws + off_agg);

        // ---- build CSR once (graph shared by both layers) ----
        hipMemsetAsync(row_start, 0, 4 * (size_t)(n_nodes + 1), stream);
        hist_kernel<<<edge_blocks, 256, 0, stream>>>(ei, flag, row_start, n_edges);
        scan1_kernel<<<nb, 1024, 0, stream>>>(row_start, blockSums, n_nodes);
        scan2_kernel<<<1, 1, 0, stream>>>(blockSums, nb, row_start, n_nodes);
        scan3_kernel<<<nb, 1024, 0, stream>>>(row_start, cursor, blockSums, n_nodes);
        fill_kernel<<<edge_blocks, 256, 0, stream>>>(ei, flag, cursor, sorted_src, n_edges);

        // ---- layer 1 ----
        agg_kernel<<<agg_blocks, 256, 0, stream>>>(x, sorted_src, row_start, agg, n_nodes);
        gemm_relu_kernel<<<gemm_blocks, 256, 0, stream>>>(x, agg, Wr1, Wl1, b1, out, n_nodes);

        // ---- layer 2 ----
        agg_kernel<<<agg_blocks, 256, 0, stream>>>(out, sorted_src, row_start, agg, n_nodes);
        gemm_relu_kernel<<<gemm_blocks, 256, 0, stream>>>(out, agg, Wr2, Wl2, b2, out, n_nodes);
    } else {
        // fallback: round-1 atomic path (needs only agg)
        float* agg = (float*)(ws + 256);
        const int scatter_blocks = (n_edges + 3) / 4;

        hipMemsetAsync(agg, 0, aggBytes, stream);
        scatter_kernel<<<scatter_blocks, 256, 0, stream>>>(x, ei, flag, agg, n_edges);
        gemm_relu_kernel<<<gemm_blocks, 256, 0, stream>>>(x, agg, Wr1, Wl1, b1, out, n_nodes);

        hipMemsetAsync(agg, 0, aggBytes, stream);
        scatter_kernel<<<scatter_blocks, 256, 0, stream>>>(out, ei, flag, agg, n_edges);
        gemm_relu_kernel<<<gemm_blocks, 256, 0, stream>>>(out, agg, Wr2, Wl2, b2, out, n_nodes);
    }
}

// Round 3
// 500.220 us; speedup vs baseline: 5.8855x; 1.6793x over previous
//
#include <hip/hip_runtime.h>

#define D 128
#define KTOT 256
#define GM 128
#define LPAD 8
#define LSTR (KTOT + LPAD)   // 264

typedef __attribute__((ext_vector_type(8))) short bf16x8;
typedef __attribute__((ext_vector_type(4))) float f32x4;

__device__ __forceinline__ unsigned short f2b(float f) {
    unsigned int u = __float_as_uint(f);
    u += 0x7fffu + ((u >> 16) & 1u);   // RNE (inputs are finite)
    return (unsigned short)(u >> 16);
}
__device__ __forceinline__ float blo(unsigned int u) { return __uint_as_float(u << 16); }
__device__ __forceinline__ float bhi(unsigned int u) { return __uint_as_float(u & 0xffff0000u); }

// ---------------------------------------------------------------------------
// Probe: int64 vs int32 edge_index layout
// ---------------------------------------------------------------------------
__global__ void detect_kernel(const unsigned int* __restrict__ ei, int* __restrict__ flag) {
    int all0 = 1;
    for (int i = 0; i < 128; ++i) {
        if (ei[2 * i + 1] != 0u) { all0 = 0; break; }
    }
    *flag = all0;
}

__device__ __forceinline__ void load_edge(const void* ei, int flag, int e, int n_edges,
                                          int& s, int& d) {
    if (flag) {
        const long long* p = (const long long*)ei;
        s = (int)p[e]; d = (int)p[n_edges + e];
    } else {
        const int* p = (const int*)ei;
        s = p[e]; d = p[n_edges + e];
    }
}

// ---------------------------------------------------------------------------
// CSR build
// ---------------------------------------------------------------------------
__global__ __launch_bounds__(256) void hist_kernel(
    const void* __restrict__ ei, const int* __restrict__ flag,
    int* __restrict__ deg, int n_edges)
{
    int e = blockIdx.x * 256 + threadIdx.x;
    if (e >= n_edges) return;
    int s, d;
    load_edge(ei, *flag, e, n_edges, s, d);
    atomicAdd(&deg[d], 1);
}

__global__ __launch_bounds__(1024) void scan1_kernel(
    int* __restrict__ arr, int* __restrict__ blockSums, int n)
{
    __shared__ int sm[1024];
    const int tid = threadIdx.x;
    const int i = blockIdx.x * 1024 + tid;
    int v = (i < n) ? arr[i] : 0;
    int val = v;
    sm[tid] = val;
    __syncthreads();
    for (int off = 1; off < 1024; off <<= 1) {
        int t = (tid >= off) ? sm[tid - off] : 0;
        __syncthreads();
        val += t;
        sm[tid] = val;
        __syncthreads();
    }
    if (i < n) arr[i] = val - v;
    if (tid == 1023) blockSums[blockIdx.x] = val;
}

__global__ void scan2_kernel(int* __restrict__ blockSums, int nb)
{
    int run = 0;
    for (int b = 0; b < nb; ++b) {
        int t = blockSums[b];
        blockSums[b] = run;
        run += t;
    }
}

__global__ __launch_bounds__(1024) void scan3_kernel(
    int* __restrict__ row_start, const int* __restrict__ blockSums, int n)
{
    const int i = blockIdx.x * 1024 + threadIdx.x;
    if (i >= n) return;
    row_start[i] += blockSums[blockIdx.x];
}

// fill mutates row_start into row_end (row_end[i] == original row_start[i+1])
__global__ __launch_bounds__(256) void fill_kernel(
    const void* __restrict__ ei, const int* __restrict__ flag,
    int* __restrict__ row_start, int* __restrict__ sorted_src, int n_edges)
{
    int e = blockIdx.x * 256 + threadIdx.x;
    if (e >= n_edges) return;
    int s, d;
    load_edge(ei, *flag, e, n_edges, s, d);
    int pos = atomicAdd(&row_start[d], 1);
    sorted_src[pos] = s;
}

// ---------------------------------------------------------------------------
// f32 -> bf16 bulk convert (8 elems/thread)
// ---------------------------------------------------------------------------
__global__ __launch_bounds__(256) void cvt_kernel(
    const float* __restrict__ in, unsigned short* __restrict__ out, long long nelem)
{
    long long i = ((long long)blockIdx.x * 256 + threadIdx.x) * 8;
    if (i >= nelem) return;
    float4 a = *(const float4*)(in + i);
    float4 b = *(const float4*)(in + i + 4);
    bf16x8 v;
    v[0] = (short)f2b(a.x); v[1] = (short)f2b(a.y);
    v[2] = (short)f2b(a.z); v[3] = (short)f2b(a.w);
    v[4] = (short)f2b(b.x); v[5] = (short)f2b(b.y);
    v[6] = (short)f2b(b.z); v[7] = (short)f2b(b.w);
    *(bf16x8*)(out + i) = v;
}

// Wt[c][k] = (k<128 ? Wr[k][c] : Wl[k-128][c]) as bf16  — [128][256]
__global__ __launch_bounds__(256) void wt_kernel(
    const float* __restrict__ Wr, const float* __restrict__ Wl,
    unsigned short* __restrict__ Wt)
{
    int c = blockIdx.x, k = threadIdx.x;
    float v = (k < 128) ? Wr[k * D + c] : Wl[(k - 128) * D + c];
    Wt[c * KTOT + k] = f2b(v);
}

// ---------------------------------------------------------------------------
// CSR gather aggregation, bf16 in / bf16 out (f32 accumulate). Wave per node.
// ---------------------------------------------------------------------------
__global__ __launch_bounds__(256) void agg_kernel(
    const unsigned short* __restrict__ src, const int* __restrict__ sorted_src,
    const int* __restrict__ row_end, unsigned short* __restrict__ dst, int n)
{
    const int node = blockIdx.x * 4 + (threadIdx.x >> 6);
    if (node >= n) return;
    const int lane = threadIdx.x & 63;
    const int beg = node ? row_end[node - 1] : 0;
    const int end = row_end[node];
    float ax = 0.f, ay = 0.f;
    int i = beg;
    for (; i + 1 < end; i += 2) {
        int s0 = sorted_src[i], s1 = sorted_src[i + 1];
        unsigned int u0 = *(const unsigned int*)(src + (long long)s0 * D + lane * 2);
        unsigned int u1 = *(const unsigned int*)(src + (long long)s1 * D + lane * 2);
        ax += blo(u0); ay += bhi(u0);
        ax += blo(u1); ay += bhi(u1);
    }
    if (i < end) {
        int s0 = sorted_src[i];
        unsigned int u0 = *(const unsigned int*)(src + (long long)s0 * D + lane * 2);
        ax += blo(u0); ay += bhi(u0);
    }
    unsigned int p = (unsigned int)f2b(ax) | ((unsigned int)f2b(ay) << 16);
    *(unsigned int*)(dst + (long long)node * D + lane * 2) = p;
}

// ---------------------------------------------------------------------------
// MFMA GEMM: out = relu([X|A] @ Wt^T + b), K=256, 128 rows/block, 8 waves.
// Xop/Aop: [n][128] bf16.  Wt: [128 cols][256 k] bf16.  bias f32[128].
// OUT_BF16=1 -> write bf16 (may alias Aop: blocks touch only their own rows).
// ---------------------------------------------------------------------------
template <int OUT_BF16>
__global__ __launch_bounds__(512) void gemm_kernel(
    const unsigned short* __restrict__ Xop, const unsigned short* __restrict__ Aop,
    const unsigned short* __restrict__ Wt, const float* __restrict__ bias,
    void* __restrict__ outp, int n)
{
    __shared__ short sIn[GM][LSTR];    // 67.6 KB
    __shared__ short sW[D][LSTR];      // 67.6 KB
    const int tid = threadIdx.x;
    const int r0 = blockIdx.x * GM;

    // stage Wt: 128 x 256 bf16 -> 4096 16B chunks
    for (int i = 0; i < 8; ++i) {
        int idx = tid + i * 512;
        int r = idx >> 5, c8 = idx & 31;
        bf16x8 w = *(const bf16x8*)(Wt + r * KTOT + c8 * 8);
        *(bf16x8*)&sW[r][c8 * 8] = w;
    }
    // stage [X|A] rows r0..r0+127 -> 4096 16B chunks
    for (int i = 0; i < 8; ++i) {
        int idx = tid + i * 512;
        int r = idx >> 5, c8 = idx & 31;
        int row = r0 + r;
        bf16x8 v = {};
        if (row < n) {
            const unsigned short* src = (c8 < 16)
                ? (Xop + (long long)row * D + c8 * 8)
                : (Aop + (long long)row * D + (c8 - 16) * 8);
            v = *(const bf16x8*)src;
        }
        *(bf16x8*)&sIn[r][c8 * 8] = v;
    }
    __syncthreads();

    const int w    = tid >> 6;
    const int lane = tid & 63;
    const int lr   = lane & 15;
    const int lk   = (lane >> 4) * 8;

    f32x4 acc[8];
    #pragma unroll
    for (int ct = 0; ct < 8; ++ct) acc[ct] = (f32x4){0.f, 0.f, 0.f, 0.f};

    #pragma unroll
    for (int ks = 0; ks < 8; ++ks) {
        bf16x8 a = *(const bf16x8*)&sIn[w * 16 + lr][ks * 32 + lk];
        #pragma unroll
        for (int ct = 0; ct < 8; ++ct) {
            bf16x8 bf = *(const bf16x8*)&sW[ct * 16 + lr][ks * 32 + lk];
            acc[ct] = __builtin_amdgcn_mfma_f32_16x16x32_bf16(a, bf, acc[ct], 0, 0, 0);
        }
    }

    // C/D: col = lane&15, row = (lane>>4)*4 + j   [m89-verified]
    const int rbase = r0 + w * 16 + (lane >> 4) * 4;
    #pragma unroll
    for (int ct = 0; ct < 8; ++ct) {
        const int col = ct * 16 + lr;
        const float bv = bias[col];
        #pragma unroll
        for (int j = 0; j < 4; ++j) {
            int row = rbase + j;
            if (row < n) {
                float val = fmaxf(acc[ct][j] + bv, 0.f);
                if (OUT_BF16) {
                    ((unsigned short*)outp)[(long long)row * D + col] = f2b(val);
                } else {
                    ((float*)outp)[(long long)row * D + col] = val;
                }
            }
        }
    }
}

static inline size_t align_up(size_t v, size_t a) { return (v + a - 1) & ~(a - 1); }

extern "C" void kernel_launch(void* const* d_in, const int* in_sizes, int n_in,
                              void* d_out, int out_size, void* d_ws, size_t ws_size,
                              hipStream_t stream) {
    const float* x   = (const float*)d_in[0];
    const void*  ei  = d_in[1];
    const float* Wr1 = (const float*)d_in[2];
    const float* Wl1 = (const float*)d_in[3];
    const float* b1  = (const float*)d_in[4];
    const float* Wr2 = (const float*)d_in[5];
    const float* Wl2 = (const float*)d_in[6];
    const float* b2  = (const float*)d_in[7];
    float* out = (float*)d_out;

    const int n_nodes = in_sizes[0] / D;
    const int n_edges = in_sizes[1] / 2;

    // ws layout (58.07 MB total; round-1/2 proved ws >= 58.4 MB via CSR path)
    char* ws = (char*)d_ws;
    size_t off_flag = 0;
    size_t off_rs   = 256;
    size_t off_bs   = align_up(off_rs + 4 * (size_t)(n_nodes + 1), 256);
    size_t off_ssrc = align_up(off_bs + 4 * 1024, 256);
    size_t off_wt   = align_up(off_ssrc + 4 * (size_t)n_edges, 256);
    size_t off_xb   = align_up(off_wt + 2 * (size_t)D * KTOT, 256);
    size_t off_ab   = align_up(off_xb + 2 * (size_t)n_nodes * D, 256);

    int* flag            = (int*)(ws + off_flag);
    int* row_start       = (int*)(ws + off_rs);
    int* blockSums       = (int*)(ws + off_bs);
    int* sorted_src      = (int*)(ws + off_ssrc);
    unsigned short* Wt   = (unsigned short*)(ws + off_wt);
    unsigned short* Xb   = (unsigned short*)(ws + off_xb);
    unsigned short* Ab   = (unsigned short*)(ws + off_ab);

    const int edge_blocks = (n_edges + 255) / 256;
    const int gemm_blocks = (n_nodes + GM - 1) / GM;
    const int agg_blocks  = (n_nodes + 3) / 4;
    const int nb          = (n_nodes + 1023) / 1024;
    const long long nfeat = (long long)n_nodes * D;

    detect_kernel<<<1, 1, 0, stream>>>((const unsigned int*)ei, flag);

    // ---- CSR build (once; shared by both layers) ----
    hipMemsetAsync(row_start, 0, 4 * (size_t)(n_nodes + 1), stream);
    hist_kernel<<<edge_blocks, 256, 0, stream>>>(ei, flag, row_start, n_edges);
    scan1_kernel<<<nb, 1024, 0, stream>>>(row_start, blockSums, n_nodes);
    scan2_kernel<<<1, 1, 0, stream>>>(blockSums, nb);
    scan3_kernel<<<nb, 1024, 0, stream>>>(row_start, blockSums, n_nodes);
    fill_kernel<<<edge_blocks, 256, 0, stream>>>(ei, flag, row_start, sorted_src, n_edges);
    // row_start now holds row_end[i]

    // ---- casts ----
    cvt_kernel<<<(int)((nfeat / 8 + 255) / 256), 256, 0, stream>>>(x, Xb, nfeat);
    wt_kernel<<<D, KTOT, 0, stream>>>(Wr1, Wl1, Wt);

    // ---- layer 1 ----
    agg_kernel<<<agg_blocks, 256, 0, stream>>>(Xb, sorted_src, row_start, Ab, n_nodes);
    gemm_kernel<1><<<gemm_blocks, 512, 0, stream>>>(Xb, Ab, Wt, b1, Ab, n_nodes);
    // Ab now holds h (bf16); Xb is dead

    // ---- layer 2 ----
    wt_kernel<<<D, KTOT, 0, stream>>>(Wr2, Wl2, Wt);
    agg_kernel<<<agg_blocks, 256, 0, stream>>>(Ab, sorted_src, row_start, Xb, n_nodes);
    gemm_kernel<0><<<gemm_blocks, 512, 0, stream>>>(Ab, Xb, Wt, b2, out, n_nodes);
}

// Round 4
// 393.160 us; speedup vs baseline: 7.4882x; 1.2723x over previous
//
#include <hip/hip_runtime.h>

#define D 128
#define KTOT 256
#define GM 128
#define LPAD 8
#define LSTR (KTOT + LPAD)   // 264
#define NPASS 4

typedef __attribute__((ext_vector_type(8))) short bf16x8;
typedef __attribute__((ext_vector_type(4))) float f32x4;

__device__ __forceinline__ unsigned short f2b(float f) {
    unsigned int u = __float_as_uint(f);
    u += 0x7fffu + ((u >> 16) & 1u);   // RNE (inputs are finite)
    return (unsigned short)(u >> 16);
}
__device__ __forceinline__ float blo(unsigned int u) { return __uint_as_float(u << 16); }
__device__ __forceinline__ float bhi(unsigned int u) { return __uint_as_float(u & 0xffff0000u); }

// ---------------------------------------------------------------------------
// Probe: int64 vs int32 edge_index layout
// ---------------------------------------------------------------------------
__global__ void detect_kernel(const unsigned int* __restrict__ ei, int* __restrict__ flag) {
    int all0 = 1;
    for (int i = 0; i < 128; ++i) {
        if (ei[2 * i + 1] != 0u) { all0 = 0; break; }
    }
    *flag = all0;
}

// ---------------------------------------------------------------------------
// Pack edge list to int32 arrays + degree histogram (fused)
// ---------------------------------------------------------------------------
__global__ __launch_bounds__(256) void pack_kernel(
    const void* __restrict__ ei, const int* __restrict__ flag,
    int* __restrict__ src32, int* __restrict__ dst32,
    int* __restrict__ deg, int n_edges)
{
    int e = blockIdx.x * 256 + threadIdx.x;
    if (e >= n_edges) return;
    int s, d;
    if (*flag) {
        const long long* p = (const long long*)ei;
        s = (int)p[e]; d = (int)p[n_edges + e];
    } else {
        const int* p = (const int*)ei;
        s = p[e]; d = p[n_edges + e];
    }
    src32[e] = s;
    dst32[e] = d;
    atomicAdd(&deg[d], 1);
}

// ---------------------------------------------------------------------------
// Scan: deg -> exclusive row_start
// ---------------------------------------------------------------------------
__global__ __launch_bounds__(1024) void scan1_kernel(
    int* __restrict__ arr, int* __restrict__ blockSums, int n)
{
    __shared__ int sm[1024];
    const int tid = threadIdx.x;
    const int i = blockIdx.x * 1024 + tid;
    int v = (i < n) ? arr[i] : 0;
    int val = v;
    sm[tid] = val;
    __syncthreads();
    for (int off = 1; off < 1024; off <<= 1) {
        int t = (tid >= off) ? sm[tid - off] : 0;
        __syncthreads();
        val += t;
        sm[tid] = val;
        __syncthreads();
    }
    if (i < n) arr[i] = val - v;
    if (tid == 1023) blockSums[blockIdx.x] = val;
}

__global__ __launch_bounds__(128) void scan2_kernel(int* __restrict__ bs, int nb)
{
    __shared__ int sm[128];
    int t = threadIdx.x;
    int v = (t < nb) ? bs[t] : 0;
    int val = v;
    sm[t] = val;
    __syncthreads();
    for (int off = 1; off < 128; off <<= 1) {
        int u = (t >= off) ? sm[t - off] : 0;
        __syncthreads();
        val += u;
        sm[t] = val;
        __syncthreads();
    }
    if (t < nb) bs[t] = val - v;
}

__global__ __launch_bounds__(1024) void scan3_kernel(
    int* __restrict__ row_start, const int* __restrict__ blockSums, int n)
{
    const int i = blockIdx.x * 1024 + threadIdx.x;
    if (i >= n) return;
    row_start[i] += blockSums[blockIdx.x];
}

// ---------------------------------------------------------------------------
// Range-partitioned CSR fill: pass handles dst in [lo, hi). Writes land in a
// contiguous ~1.6 MB slice of sorted_src -> L2-resident, no line thrash.
// Mutates row_start into row_end over the union of passes.
// ---------------------------------------------------------------------------
__global__ __launch_bounds__(256) void fill_pass_kernel(
    const int* __restrict__ src32, const int* __restrict__ dst32,
    int* __restrict__ row_start, int* __restrict__ sorted_src,
    int n_edges, int lo, int hi)
{
    int e = blockIdx.x * 256 + threadIdx.x;
    if (e >= n_edges) return;
    int d = dst32[e];
    if (d >= lo && d < hi) {
        int pos = atomicAdd(&row_start[d], 1);
        sorted_src[pos] = src32[e];
    }
}

// ---------------------------------------------------------------------------
// f32 -> bf16 bulk convert (8 elems/thread)
// ---------------------------------------------------------------------------
__global__ __launch_bounds__(256) void cvt_kernel(
    const float* __restrict__ in, unsigned short* __restrict__ out, long long nelem)
{
    long long i = ((long long)blockIdx.x * 256 + threadIdx.x) * 8;
    if (i >= nelem) return;
    float4 a = *(const float4*)(in + i);
    float4 b = *(const float4*)(in + i + 4);
    bf16x8 v;
    v[0] = (short)f2b(a.x); v[1] = (short)f2b(a.y);
    v[2] = (short)f2b(a.z); v[3] = (short)f2b(a.w);
    v[4] = (short)f2b(b.x); v[5] = (short)f2b(b.y);
    v[6] = (short)f2b(b.z); v[7] = (short)f2b(b.w);
    *(bf16x8*)(out + i) = v;
}

// Wt[c][k] = (k<128 ? Wr[k][c] : Wl[k-128][c]) as bf16  — [128][256]
__global__ __launch_bounds__(256) void wt_kernel(
    const float* __restrict__ Wr, const float* __restrict__ Wl,
    unsigned short* __restrict__ Wt)
{
    int c = blockIdx.x, k = threadIdx.x;
    float v = (k < 128) ? Wr[k * D + c] : Wl[(k - 128) * D + c];
    Wt[c * KTOT + k] = f2b(v);
}

// ---------------------------------------------------------------------------
// CSR gather aggregation: wave per node, 16 lanes x uint4 per row,
// 4 edges per iteration, unrolled x2 (8 rows in flight).
// ---------------------------------------------------------------------------
__global__ __launch_bounds__(256) void agg_kernel(
    const unsigned short* __restrict__ src, const int* __restrict__ sorted_src,
    const int* __restrict__ row_end, unsigned short* __restrict__ dst, int n)
{
    const int node = blockIdx.x * 4 + (threadIdx.x >> 6);
    if (node >= n) return;
    const int lane = threadIdx.x & 63;
    const int j = lane >> 4;           // edge slot 0..3
    const int c = (lane & 15) * 8;     // 8 bf16 columns
    const int beg = node ? row_end[node - 1] : 0;
    const int end = row_end[node];

    float a0 = 0.f, a1 = 0.f, a2 = 0.f, a3 = 0.f,
          a4 = 0.f, a5 = 0.f, a6 = 0.f, a7 = 0.f;

    int i = beg + j;
    for (; i + 4 < end; i += 8) {
        int s0 = sorted_src[i];
        int s1 = sorted_src[i + 4];
        uint4 u0 = *(const uint4*)(src + (long long)s0 * D + c);
        uint4 u1 = *(const uint4*)(src + (long long)s1 * D + c);
        a0 += blo(u0.x); a1 += bhi(u0.x); a2 += blo(u0.y); a3 += bhi(u0.y);
        a4 += blo(u0.z); a5 += bhi(u0.z); a6 += blo(u0.w); a7 += bhi(u0.w);
        a0 += blo(u1.x); a1 += bhi(u1.x); a2 += blo(u1.y); a3 += bhi(u1.y);
        a4 += blo(u1.z); a5 += bhi(u1.z); a6 += blo(u1.w); a7 += bhi(u1.w);
    }
    if (i < end) {
        int s0 = sorted_src[i];
        uint4 u0 = *(const uint4*)(src + (long long)s0 * D + c);
        a0 += blo(u0.x); a1 += bhi(u0.x); a2 += blo(u0.y); a3 += bhi(u0.y);
        a4 += blo(u0.z); a5 += bhi(u0.z); a6 += blo(u0.w); a7 += bhi(u0.w);
    }

    // combine the 4 edge slots (lanes differing in bits 4 and 5)
    a0 += __shfl_xor(a0, 16); a1 += __shfl_xor(a1, 16);
    a2 += __shfl_xor(a2, 16); a3 += __shfl_xor(a3, 16);
    a4 += __shfl_xor(a4, 16); a5 += __shfl_xor(a5, 16);
    a6 += __shfl_xor(a6, 16); a7 += __shfl_xor(a7, 16);
    a0 += __shfl_xor(a0, 32); a1 += __shfl_xor(a1, 32);
    a2 += __shfl_xor(a2, 32); a3 += __shfl_xor(a3, 32);
    a4 += __shfl_xor(a4, 32); a5 += __shfl_xor(a5, 32);
    a6 += __shfl_xor(a6, 32); a7 += __shfl_xor(a7, 32);

    if (j == 0) {
        uint4 p;
        p.x = (unsigned int)f2b(a0) | ((unsigned int)f2b(a1) << 16);
        p.y = (unsigned int)f2b(a2) | ((unsigned int)f2b(a3) << 16);
        p.z = (unsigned int)f2b(a4) | ((unsigned int)f2b(a5) << 16);
        p.w = (unsigned int)f2b(a6) | ((unsigned int)f2b(a7) << 16);
        *(uint4*)(dst + (long long)node * D + c) = p;
    }
}

// ---------------------------------------------------------------------------
// MFMA GEMM: out = relu([X|A] @ Wt^T + b), K=256, 128 rows/block, 8 waves.
// ---------------------------------------------------------------------------
template <int OUT_BF16>
__global__ __launch_bounds__(512) void gemm_kernel(
    const unsigned short* __restrict__ Xop, const unsigned short* __restrict__ Aop,
    const unsigned short* __restrict__ Wt, const float* __restrict__ bias,
    void* __restrict__ outp, int n)
{
    __shared__ short sIn[GM][LSTR];
    __shared__ short sW[D][LSTR];
    const int tid = threadIdx.x;
    const int r0 = blockIdx.x * GM;

    for (int i = 0; i < 8; ++i) {
        int idx = tid + i * 512;
        int r = idx >> 5, c8 = idx & 31;
        bf16x8 w = *(const bf16x8*)(Wt + r * KTOT + c8 * 8);
        *(bf16x8*)&sW[r][c8 * 8] = w;
    }
    for (int i = 0; i < 8; ++i) {
        int idx = tid + i * 512;
        int r = idx >> 5, c8 = idx & 31;
        int row = r0 + r;
        bf16x8 v = {};
        if (row < n) {
            const unsigned short* src = (c8 < 16)
                ? (Xop + (long long)row * D + c8 * 8)
                : (Aop + (long long)row * D + (c8 - 16) * 8);
            v = *(const bf16x8*)src;
        }
        *(bf16x8*)&sIn[r][c8 * 8] = v;
    }
    __syncthreads();

    const int w    = tid >> 6;
    const int lane = tid & 63;
    const int lr   = lane & 15;
    const int lk   = (lane >> 4) * 8;

    f32x4 acc[8];
    #pragma unroll
    for (int ct = 0; ct < 8; ++ct) acc[ct] = (f32x4){0.f, 0.f, 0.f, 0.f};

    #pragma unroll
    for (int ks = 0; ks < 8; ++ks) {
        bf16x8 a = *(const bf16x8*)&sIn[w * 16 + lr][ks * 32 + lk];
        #pragma unroll
        for (int ct = 0; ct < 8; ++ct) {
            bf16x8 bf = *(const bf16x8*)&sW[ct * 16 + lr][ks * 32 + lk];
            acc[ct] = __builtin_amdgcn_mfma_f32_16x16x32_bf16(a, bf, acc[ct], 0, 0, 0);
        }
    }

    const int rbase = r0 + w * 16 + (lane >> 4) * 4;
    #pragma unroll
    for (int ct = 0; ct < 8; ++ct) {
        const int col = ct * 16 + lr;
        const float bv = bias[col];
        #pragma unroll
        for (int j = 0; j < 4; ++j) {
            int row = rbase + j;
            if (row < n) {
                float val = fmaxf(acc[ct][j] + bv, 0.f);
                if (OUT_BF16) {
                    ((unsigned short*)outp)[(long long)row * D + col] = f2b(val);
                } else {
                    ((float*)outp)[(long long)row * D + col] = val;
                }
            }
        }
    }
}

static inline size_t align_up(size_t v, size_t a) { return (v + a - 1) & ~(a - 1); }

extern "C" void kernel_launch(void* const* d_in, const int* in_sizes, int n_in,
                              void* d_out, int out_size, void* d_ws, size_t ws_size,
                              hipStream_t stream) {
    const float* x   = (const float*)d_in[0];
    const void*  ei  = d_in[1];
    const float* Wr1 = (const float*)d_in[2];
    const float* Wl1 = (const float*)d_in[3];
    const float* b1  = (const float*)d_in[4];
    const float* Wr2 = (const float*)d_in[5];
    const float* Wl2 = (const float*)d_in[6];
    const float* b2  = (const float*)d_in[7];
    float* out = (float*)d_out;

    const int n_nodes = in_sizes[0] / D;
    const int n_edges = in_sizes[1] / 2;

    // ws layout (58.07 MB; proven available by rounds 2-3)
    char* ws = (char*)d_ws;
    size_t off_flag = 0;
    size_t off_rs   = 256;
    size_t off_bs   = align_up(off_rs + 4 * (size_t)(n_nodes + 1), 256);
    size_t off_ssrc = align_up(off_bs + 4 * 1024, 256);
    size_t off_wt   = align_up(off_ssrc + 4 * (size_t)n_edges, 256);
    size_t off_xb   = align_up(off_wt + 2 * (size_t)D * KTOT, 256);
    size_t off_ab   = align_up(off_xb + 2 * (size_t)n_nodes * D, 256);

    int* flag            = (int*)(ws + off_flag);
    int* row_start       = (int*)(ws + off_rs);
    int* blockSums       = (int*)(ws + off_bs);
    int* sorted_src      = (int*)(ws + off_ssrc);
    unsigned short* Wt   = (unsigned short*)(ws + off_wt);
    unsigned short* Xb   = (unsigned short*)(ws + off_xb);
    unsigned short* Ab   = (unsigned short*)(ws + off_ab);
    // src32/dst32 alias the Xb region (dead until cvt_kernel runs)
    int* src32 = (int*)(ws + off_xb);
    int* dst32 = src32 + n_edges;

    const int edge_blocks = (n_edges + 255) / 256;
    const int gemm_blocks = (n_nodes + GM - 1) / GM;
    const int agg_blocks  = (n_nodes + 3) / 4;
    const int nb          = (n_nodes + 1023) / 1024;
    const long long nfeat = (long long)n_nodes * D;

    detect_kernel<<<1, 1, 0, stream>>>((const unsigned int*)ei, flag);

    // ---- CSR build (once) ----
    hipMemsetAsync(row_start, 0, 4 * (size_t)(n_nodes + 1), stream);
    pack_kernel<<<edge_blocks, 256, 0, stream>>>(ei, flag, src32, dst32, row_start, n_edges);
    scan1_kernel<<<nb, 1024, 0, stream>>>(row_start, blockSums, n_nodes);
    scan2_kernel<<<1, 128, 0, stream>>>(blockSums, nb);
    scan3_kernel<<<nb, 1024, 0, stream>>>(row_start, blockSums, n_nodes);
    const int rng = (n_nodes + NPASS - 1) / NPASS;
    for (int p = 0; p < NPASS; ++p) {
        fill_pass_kernel<<<edge_blocks, 256, 0, stream>>>(
            src32, dst32, row_start, sorted_src, n_edges, p * rng, (p + 1) * rng);
    }
    // row_start now holds row_end[i]

    // ---- casts (cvt overwrites src32/dst32 — they are dead now) ----
    cvt_kernel<<<(int)((nfeat / 8 + 255) / 256), 256, 0, stream>>>(x, Xb, nfeat);
    wt_kernel<<<D, KTOT, 0, stream>>>(Wr1, Wl1, Wt);

    // ---- layer 1 ----
    agg_kernel<<<agg_blocks, 256, 0, stream>>>(Xb, sorted_src, row_start, Ab, n_nodes);
    gemm_kernel<1><<<gemm_blocks, 512, 0, stream>>>(Xb, Ab, Wt, b1, Ab, n_nodes);

    // ---- layer 2 ----
    wt_kernel<<<D, KTOT, 0, stream>>>(Wr2, Wl2, Wt);
    agg_kernel<<<agg_blocks, 256, 0, stream>>>(Ab, sorted_src, row_start, Xb, n_nodes);
    gemm_kernel<0><<<gemm_blocks, 512, 0, stream>>>(Ab, Xb, Wt, b2, out, n_nodes);
}